// Round 5
// baseline (66.691 us; speedup 1.0000x reference)
//
#include <hip/hip_runtime.h>
#include <math.h>

#define S 96
#define SM 95
#define PT 8            // threads per ray
#define NS 12           // midpoints/samples per thread
#define RPB 32          // rays per block
#define TPB 256
#define DROW 97         // padded LDS row stride for d/s (floats)
#define TLP 99          // padded LDS row stride for TL (floats)
#define L2E 1.4426950408889634f

__device__ __forceinline__ float fexp2(float x) {
#if __has_builtin(__builtin_amdgcn_exp2f)
    return __builtin_amdgcn_exp2f(x);   // v_exp_f32: 2^x
#else
    return exp2f(x);
#endif
}

__device__ __forceinline__ float flog2(float x) {
#if __has_builtin(__builtin_amdgcn_logf)
    return __builtin_amdgcn_logf(x);    // v_log_f32: log2(x)
#else
    return log2f(x);
#endif
}

// ws[0] = global min depth bits, ws[1] = global max depth bits
__global__ void init_ws_kernel(unsigned int* ws) {
    ws[0] = 0x7F800000u;  // +inf
    ws[1] = 0xFF800000u;  // -inf
}

// ---------------------------------------------------------------------------
// Block = 32 rays, 8 threads/ray.
// Phase A: coalesced float4 load of d,s -> bank-padded LDS; block min/max of
//          depth boundaries -> device atomics into ws.
// Pass 1:  thread p owns midpoints 12p..12p+11: dd2 = delta*log2(1+e^x),
//          serial cumsum, 3-step group scan -> boundary transmittances
//          TL[r][m] = T_{m-1} (m=0..97, T_{-1}:=T_0=1, T_96:=T_95) in LDS.
// Pass 2:  thread p handles samples j = p+8m (dense global color reads):
//          v_j = 0.5*(TL[j]-TL[j+2]), w_j = TL[j+1]-TL[j+2];
//          accumulate rgb/depth, 3-step group reduce.
// Depth written UNCLAMPED (NaN->inf); clamp_kernel applies global min/max.
// ---------------------------------------------------------------------------
__global__ __launch_bounds__(256) void march_kernel(
    const float* __restrict__ colors,
    const float* __restrict__ dens,
    const float* __restrict__ depths,
    const int* __restrict__ white_back,
    unsigned int* __restrict__ ws,
    float* __restrict__ out_rgb,   // [nrays,3]
    float* __restrict__ out_dep,   // [nrays] (raw)
    float* __restrict__ out_w,     // [nrays,95]
    int nrays) {
    __shared__ float d_l[RPB * DROW];     // 12416 B
    __shared__ float sl_tl[RPB * TLP];    // 12672 B: s (stride DROW), then TL

    const int t = threadIdx.x;
    const size_t rayBase = (size_t)blockIdx.x * RPB;

    const float* dg = depths + rayBase * S;
    const float* sg = dens + rayBase * S;

    // ---- Phase A: stage d, s (3072 floats each, contiguous per block)
#pragma unroll
    for (int k = 0; k < 3; k++) {
        int idx4 = t + k * TPB;          // 0..767 (float4 index)
        int r = idx4 / 24;               // 24 float4 per 96-float row
        int c = (idx4 % 24) * 4;
        float4 vd = ((const float4*)dg)[idx4];
        float4 vs = ((const float4*)sg)[idx4];
        float* dp = &d_l[r * DROW + c];
        dp[0] = vd.x; dp[1] = vd.y; dp[2] = vd.z; dp[3] = vd.w;
        float* sp = &sl_tl[r * DROW + c];
        sp[0] = vs.x; sp[1] = vs.y; sp[2] = vs.z; sp[3] = vs.w;
    }
    if (t < RPB) {  // zero the neighbor-overrun column
        d_l[t * DROW + 96] = 0.f;
        sl_tl[t * DROW + 96] = 0.f;
    }
    __syncthreads();  // B1

    // ---- block min/max of depth boundaries (depths sorted along sample axis)
    if (t < RPB) {
        float mn = d_l[t * DROW];
        float mx = d_l[t * DROW + 95];
#pragma unroll
        for (int off = 16; off >= 1; off >>= 1) {
            mn = fminf(mn, __shfl_xor(mn, off));
            mx = fmaxf(mx, __shfl_xor(mx, off));
        }
        if (t == 0) {
            atomicMin((int*)&ws[0], __float_as_int(mn));
            atomicMax((int*)&ws[1], __float_as_int(mx));
        }
    }

    // ---- Pass 1: dd2 + per-thread cumsum
    const int r = t >> 3, p = t & 7;
    const float* dr = &d_l[r * DROW + p * NS];
    const float* sr = &sl_tl[r * DROW + p * NS];
    const float C1 = 0.5f * L2E;
    float cum[NS];
    float run = 0.f;
    float d_prev = dr[0], s_prev = sr[0];
#pragma unroll
    for (int i = 0; i < NS; i++) {
        float d_nx = dr[i + 1];
        float s_nx = sr[i + 1];
        float x2 = (s_prev + s_nx) * C1;
        float sp_ = fmaxf(x2, 0.f) + flog2(1.f + fexp2(-fabsf(x2)));
        float dd = (d_nx - d_prev) * sp_;
        if (p == PT - 1 && i == NS - 1) dd = 0.f;  // midpoint 95 doesn't exist
        run += dd;
        cum[i] = run;
        d_prev = d_nx; s_prev = s_nx;
    }

    // 8-lane inclusive scan -> exclusive base
    float tot = run;
#pragma unroll
    for (int off = 1; off < PT; off <<= 1) {
        float q = __shfl_up(tot, off);
        if (p >= off) tot += q;
    }
    float base = tot - run;

    __syncthreads();  // B2: all s reads done; sl_tl region becomes TL
    float* TL = sl_tl;
    if (p == 0) {
        TL[r * TLP + 0] = 1.f;   // T_{-1} := 1
        TL[r * TLP + 1] = 1.f;   // T_0 = 1
    }
#pragma unroll
    for (int i = 0; i < NS; i++)
        TL[r * TLP + 12 * p + 2 + i] = fexp2(-(base + cum[i]));
    __syncthreads();  // B3

    // ---- Pass 2: samples j = p + 8m (dense color reads, no neighbors needed)
    const size_t rayG = rayBase + r;
    const float* crow = colors + rayG * (S * 3);
    const float* TLr = &TL[r * TLP];
    const float* dlr = &d_l[r * DROW];
    float* wrow = out_w + rayG * SM;
    float racc = 0.f, gacc = 0.f, bacc = 0.f, dacc = 0.f;
#pragma unroll
    for (int m = 0; m < NS; m++) {
        int j = p + 8 * m;
        float T0 = TLr[j];        // T_{j-1}
        float T1 = TLr[j + 1];    // T_j
        float T2 = TLr[j + 2];    // T_{j+1}
        float v = 0.5f * (T0 - T2);
        float3 c = *(const float3*)&crow[3 * j];
        float dj = dlr[j];
        racc += v * c.x;
        gacc += v * c.y;
        bacc += v * c.z;
        dacc += v * dj;
        if (j < SM) wrow[j] = T1 - T2;   // only (p=7,m=11) skips
    }

    // ---- reduce across the 8-lane group
#pragma unroll
    for (int off = 1; off < PT; off <<= 1) {
        racc += __shfl_xor(racc, off);
        gacc += __shfl_xor(gacc, off);
        bacc += __shfl_xor(bacc, off);
        dacc += __shfl_xor(dacc, off);
    }

    if (p == 0 && rayG < (size_t)nrays) {
        float rr = racc, gg = gacc, bb = bacc;
        if (*white_back) {
            float T95 = TLr[96];   // 1 - wtot = T_95 (telescoping)
            rr += T95; gg += T95; bb += T95;
        }
        out_rgb[rayG * 3 + 0] = rr;
        out_rgb[rayG * 3 + 1] = gg;
        out_rgb[rayG * 3 + 2] = bb;
        float cd = dacc;
        if (isnan(cd)) cd = INFINITY;   // nan_to_num(nan=inf)
        out_dep[rayG] = cd;
    }
}

// Apply the global depth clip after ws is final.
__global__ void clamp_kernel(float* __restrict__ dep,
                             const unsigned int* __restrict__ ws, int n) {
    int i = blockIdx.x * blockDim.x + threadIdx.x;
    if (i < n) {
        float gmin = __int_as_float((int)ws[0]);
        float gmax = __int_as_float((int)ws[1]);
        dep[i] = fminf(fmaxf(dep[i], gmin), gmax);
    }
}

extern "C" void kernel_launch(void* const* d_in, const int* in_sizes, int n_in,
                              void* d_out, int out_size, void* d_ws, size_t ws_size,
                              hipStream_t stream) {
    const float* colors = (const float*)d_in[0];
    const float* dens = (const float*)d_in[1];
    const float* depths = (const float*)d_in[2];
    const int* white_back = (const int*)d_in[3];

    const int nrays = in_sizes[1] / S;  // densities: nrays * S
    unsigned int* ws = (unsigned int*)d_ws;

    float* out_rgb = (float*)d_out;                // nrays*3
    float* out_dep = out_rgb + (size_t)nrays * 3;  // nrays
    float* out_w = out_dep + nrays;                // nrays*95

    init_ws_kernel<<<1, 1, 0, stream>>>(ws);

    const int blocks = (nrays + RPB - 1) / RPB;
    march_kernel<<<blocks, TPB, 0, stream>>>(
        colors, dens, depths, white_back, ws, out_rgb, out_dep, out_w, nrays);

    clamp_kernel<<<(nrays + 255) / 256, 256, 0, stream>>>(out_dep, ws, nrays);
}

// Round 6
// 36.611 us; speedup vs baseline: 1.8216x; 1.8216x over previous
//
#include <hip/hip_runtime.h>
#include <math.h>

#define S 96
#define SM 95
#define L2E 1.4426950408889634f

__device__ __forceinline__ float fexp2(float x) {
#if __has_builtin(__builtin_amdgcn_exp2f)
    return __builtin_amdgcn_exp2f(x);   // v_exp_f32: 2^x
#else
    return exp2f(x);
#endif
}
__device__ __forceinline__ float flog2(float x) {
#if __has_builtin(__builtin_amdgcn_logf)
    return __builtin_amdgcn_logf(x);    // v_log_f32: log2(x)
#else
    return log2f(x);
#endif
}

// DPP helper: dest = (lane selected by CTRL, masked by RMASK) else 0.
template <int CTRL, int RMASK>
__device__ __forceinline__ float updpp0(float src) {
    return __int_as_float(__builtin_amdgcn_update_dpp(
        0, __float_as_int(src), CTRL, RMASK, 0xF, false));
}

// 64-lane inclusive prefix-sum, canonical gfx9 DPP pattern (all VALU, no DS).
__device__ __forceinline__ float dpp_scan_add(float x) {
    x += updpp0<0x111, 0xF>(x);  // row_shr:1
    x += updpp0<0x112, 0xF>(x);  // row_shr:2
    x += updpp0<0x114, 0xF>(x);  // row_shr:4
    x += updpp0<0x118, 0xF>(x);  // row_shr:8
    x += updpp0<0x142, 0xA>(x);  // row_bcast:15 -> rows 1,3
    x += updpp0<0x143, 0xC>(x);  // row_bcast:31 -> rows 2,3
    return x;                    // lane 63 holds the wave total
}

__device__ __forceinline__ float rdlane(float x, int lane) {
    return __int_as_float(__builtin_amdgcn_readlane(__float_as_int(x), lane));
}

__device__ __forceinline__ float wave_sum(float x) {
    return rdlane(dpp_scan_add(x), 63);   // uniform total
}

// atomic-fallback init (only used if ws is too small for slots)
__global__ void init_ws_kernel(unsigned int* ws) {
    ws[0] = 0x7F800000u;  // +inf
    ws[1] = 0xFF800000u;  // -inf
}

// ---------------------------------------------------------------------------
// One wave per ray (4 rays / 256-thread block). Samples j=0..95:
// batch a = lane l (j=l); batch b = lane l (j=64+l, valid l<32).
//
// Log-space: dd2_i = (d_{i+1}-d_i)*log2(1+exp(x_i)), x_i=(s_i+s_{i+1})/2.
// T_j = exp2(-prefix(dd2)).  w_i = T_i - T_{i+1}.
// rgb/depth: v_j = 0.5*(T_{j-1}-T_{j+1}) per-sample coefficients.
// wtot telescopes: 1-wtot = T_95.
// Per-ray depth bounds d[0](lane0)/d[95](lane31) -> block min/max -> ws slots
// (or atomics in fallback mode). Depth written unclamped; clamp_kernel last.
// ---------------------------------------------------------------------------
template <bool SLOT>
__global__ __launch_bounds__(256) void march_kernel(
    const float* __restrict__ colors,
    const float* __restrict__ dens,
    const float* __restrict__ depths,
    const int* __restrict__ white_back,
    unsigned int* __restrict__ ws,
    float* __restrict__ out_rgb,   // [nrays,3]
    float* __restrict__ out_dep,   // [nrays] raw
    float* __restrict__ out_w,     // [nrays,95]
    int nrays, int nblocks) {
    __shared__ float smn[4], smx[4];
    const int wv = threadIdx.x >> 6;
    const int l = threadIdx.x & 63;
    const int ray = blockIdx.x * 4 + wv;
    const bool valid = (ray < nrays);

    const float* db = depths + (size_t)ray * S;
    const float* sb = dens + (size_t)ray * S;
    const float* cb = colors + (size_t)ray * (S * 3);

    float d_a = INFINITY, s_a = 0.f, c0_a = 0.f, c1_a = 0.f, c2_a = 0.f;
    float d_b = -INFINITY, s_b = 0.f, c0_b = 0.f, c1_b = 0.f, c2_b = 0.f;
    const bool hb = (l < 32);
    if (valid) {
        d_a = db[l];
        s_a = sb[l];
        c0_a = cb[3 * l + 0];
        c1_a = cb[3 * l + 1];
        c2_a = cb[3 * l + 2];
        if (hb) {
            d_b = db[64 + l];
            s_b = sb[64 + l];
            c0_b = cb[192 + 3 * l + 0];
            c1_b = cb[192 + 3 * l + 1];
            c2_b = cb[192 + 3 * l + 2];
        } else {
            d_b = 0.f;
        }
    }

    // ---- per-ray depth bounds (sorted): d[0] = lane0 d_a, d[95] = lane31 d_b
    float rmn = rdlane(d_a, 0);
    float rmx = rdlane(d_b, 31);
    if (l == 0) { smn[wv] = rmn; smx[wv] = rmx; }
    __syncthreads();
    if (threadIdx.x == 0) {
        float mn = fminf(fminf(smn[0], smn[1]), fminf(smn[2], smn[3]));
        float mx = fmaxf(fmaxf(smx[0], smx[1]), fmaxf(smx[2], smx[3]));
        if (SLOT) {
            float* slots = (float*)ws;
            slots[2 + blockIdx.x] = mn;
            slots[2 + nblocks + blockIdx.x] = mx;
        } else {
            atomicMin((int*)&ws[0], __float_as_int(mn));
            atomicMax((int*)&ws[1], __float_as_int(mx));
        }
    }
    if (!valid) return;

    // ---- neighbor depth/density (the only remaining DS shuffles)
    float dn_a = __shfl_down(d_a, 1);
    float sn_a = __shfl_down(s_a, 1);
    {
        float d64 = rdlane(d_b, 0);
        float s64 = rdlane(s_b, 0);
        if (l == 63) { dn_a = d64; sn_a = s64; }
    }
    float dn_b = __shfl_down(d_b, 1);
    float sn_b = __shfl_down(s_b, 1);

    // ---- log2-space density*delta per midpoint
    const float C1 = 0.5f * L2E;
    float x_a = (s_a + sn_a) * C1;
    float lg_a = fmaxf(x_a, 0.f) + flog2(1.f + fexp2(-fabsf(x_a)));
    float dd_a = (dn_a - d_a) * lg_a;                    // midpoint l

    float x_b = (s_b + sn_b) * C1;
    float lg_b = fmaxf(x_b, 0.f) + flog2(1.f + fexp2(-fabsf(x_b)));
    float dd_b = (l <= 30) ? (dn_b - d_b) * lg_b : 0.f;  // midpoint 64+l

    // ---- DPP scans (VALU pipe)
    float A = dpp_scan_add(dd_a);        // inclusive; lane l = sum dd[0..l]
    float P = rdlane(A, 63);             // batch-a total
    float Bc = dpp_scan_add(dd_b);

    float Ti_a = fexp2(-A);              // T_{l+1}
    float Ti_b = fexp2(-(P + Bc));       // T_{65+l}  (l=31 -> T_96 := T_95)
    float T63 = rdlane(Ti_a, 62);
    float T64 = rdlane(Ti_a, 63);
    float T95 = rdlane(Ti_b, 31);

    float Te_a = __shfl_up(Ti_a, 1);     // T_l
    if (l == 0) Te_a = 1.f;
    float Te_b = __shfl_up(Ti_b, 1);     // T_{64+l}
    if (l == 0) Te_b = T64;
    float Tm1_a = __shfl_up(Ti_a, 2);    // T_{l-1}
    if (l <= 1) Tm1_a = 1.f;             // T_{-1} := T_0 = 1
    float Tm1_b = __shfl_up(Ti_b, 2);    // T_{63+l}
    if (l == 0) Tm1_b = T63;
    if (l == 1) Tm1_b = T64;

    float w_a = Te_a - Ti_a;             // weight of midpoint l
    float w_b = Te_b - Ti_b;             // weight of midpoint 64+l (l<=30)

    float v_a = 0.5f * (Tm1_a - Ti_a);          // coeff of sample l
    float v_b = hb ? 0.5f * (Tm1_b - Ti_b) : 0.f;  // coeff of sample 64+l

    // ---- weighted sums over samples (DPP reductions, VALU pipe)
    float r_sum = wave_sum(v_a * c0_a + v_b * c0_b);
    float g_sum = wave_sum(v_a * c1_a + v_b * c1_b);
    float b_sum = wave_sum(v_a * c2_a + v_b * c2_b);
    float dep_sum = wave_sum(v_a * d_a + v_b * d_b);

    // ---- outputs
    float* wout = out_w + (size_t)ray * SM;
    wout[l] = w_a;                    // midpoints 0..63
    if (l <= 30) wout[64 + l] = w_b;  // midpoints 64..94

    if (l == 0) {
        float rr = r_sum, gg = g_sum, bb = b_sum;
        if (*white_back) {
            rr += T95; gg += T95; bb += T95;   // 1 - wtot = T_95
        }
        out_rgb[(size_t)ray * 3 + 0] = rr;
        out_rgb[(size_t)ray * 3 + 1] = gg;
        out_rgb[(size_t)ray * 3 + 2] = bb;
        float cd = dep_sum;
        if (isnan(cd)) cd = INFINITY;   // nan_to_num(nan=inf)
        out_dep[ray] = cd;              // clamped later
    }
}

// Reduce the per-block min/max slots into ws[0], ws[1]. Single block.
__global__ __launch_bounds__(1024) void minmax_finalize(unsigned int* ws,
                                                        int nblocks) {
    const float* mns = (const float*)ws + 2;
    const float* mxs = mns + nblocks;
    float mn = INFINITY, mx = -INFINITY;
    for (int i = threadIdx.x; i < nblocks; i += blockDim.x) {
        mn = fminf(mn, mns[i]);
        mx = fmaxf(mx, mxs[i]);
    }
#pragma unroll
    for (int off = 32; off >= 1; off >>= 1) {
        mn = fminf(mn, __shfl_xor(mn, off));
        mx = fmaxf(mx, __shfl_xor(mx, off));
    }
    __shared__ float a[16], b[16];
    const int w = threadIdx.x >> 6;
    if ((threadIdx.x & 63) == 0) { a[w] = mn; b[w] = mx; }
    __syncthreads();
    if (threadIdx.x == 0) {
        const int nw = (blockDim.x + 63) >> 6;
        for (int i = 1; i < nw; i++) {
            mn = fminf(mn, a[i]);
            mx = fmaxf(mx, b[i]);
        }
        ws[0] = (unsigned int)__float_as_int(mn);
        ws[1] = (unsigned int)__float_as_int(mx);
    }
}

// Apply the global depth clip after ws[0..1] is final.
__global__ void clamp_kernel(float* __restrict__ dep,
                             const unsigned int* __restrict__ ws, int n) {
    int i = blockIdx.x * blockDim.x + threadIdx.x;
    if (i < n) {
        float gmin = __int_as_float((int)ws[0]);
        float gmax = __int_as_float((int)ws[1]);
        dep[i] = fminf(fmaxf(dep[i], gmin), gmax);
    }
}

extern "C" void kernel_launch(void* const* d_in, const int* in_sizes, int n_in,
                              void* d_out, int out_size, void* d_ws, size_t ws_size,
                              hipStream_t stream) {
    const float* colors = (const float*)d_in[0];
    const float* dens = (const float*)d_in[1];
    const float* depths = (const float*)d_in[2];
    const int* white_back = (const int*)d_in[3];

    const int nrays = in_sizes[1] / S;  // densities: nrays * S
    unsigned int* ws = (unsigned int*)d_ws;

    float* out_rgb = (float*)d_out;                // nrays*3
    float* out_dep = out_rgb + (size_t)nrays * 3;  // nrays
    float* out_w = out_dep + nrays;                // nrays*95

    const int nblocks = (nrays + 3) / 4;           // 4 rays (waves) per block
    const bool slot = ws_size >= (size_t)(2 + 2 * nblocks) * sizeof(float);

    if (slot) {
        march_kernel<true><<<nblocks, 256, 0, stream>>>(
            colors, dens, depths, white_back, ws, out_rgb, out_dep, out_w,
            nrays, nblocks);
        minmax_finalize<<<1, 1024, 0, stream>>>(ws, nblocks);
    } else {
        init_ws_kernel<<<1, 1, 0, stream>>>(ws);
        march_kernel<false><<<nblocks, 256, 0, stream>>>(
            colors, dens, depths, white_back, ws, out_rgb, out_dep, out_w,
            nrays, nblocks);
    }
    clamp_kernel<<<(nrays + 255) / 256, 256, 0, stream>>>(out_dep, ws, nrays);
}

// Round 7
// 36.074 us; speedup vs baseline: 1.8487x; 1.0149x over previous
//
#include <hip/hip_runtime.h>
#include <math.h>

#define S 96
#define SM 95
#define RPW 8            // rays per wave
#define L2E 1.4426950408889634f

__device__ __forceinline__ float fexp2(float x) {
#if __has_builtin(__builtin_amdgcn_exp2f)
    return __builtin_amdgcn_exp2f(x);   // v_exp_f32: 2^x
#else
    return exp2f(x);
#endif
}
__device__ __forceinline__ float flog2(float x) {
#if __has_builtin(__builtin_amdgcn_logf)
    return __builtin_amdgcn_logf(x);    // v_log_f32: log2(x)
#else
    return log2f(x);
#endif
}

// DPP helper: dest = lane selected by CTRL (invalid lanes -> 0).
template <int CTRL, int RMASK>
__device__ __forceinline__ float updpp0(float src) {
    return __int_as_float(__builtin_amdgcn_update_dpp(
        0, __float_as_int(src), CTRL, RMASK, 0xF, false));
}

// 64-lane inclusive prefix-sum (all VALU, canonical gfx9 DPP ladder).
__device__ __forceinline__ float dpp_scan_add(float x) {
    x += updpp0<0x111, 0xF>(x);  // row_shr:1
    x += updpp0<0x112, 0xF>(x);  // row_shr:2
    x += updpp0<0x114, 0xF>(x);  // row_shr:4
    x += updpp0<0x118, 0xF>(x);  // row_shr:8
    x += updpp0<0x142, 0xA>(x);  // row_bcast:15 -> rows 1,3
    x += updpp0<0x143, 0xC>(x);  // row_bcast:31 -> rows 2,3
    return x;                    // lane 63 = wave total
}

__device__ __forceinline__ float rdlane(float x, int lane) {
    return __int_as_float(__builtin_amdgcn_readlane(__float_as_int(x), lane));
}
__device__ __forceinline__ float wave_sum(float x) {
    return rdlane(dpp_scan_add(x), 63);
}
// wave-wide lane shifts (VALU, no DS): shr = shfl_up(1), shl = shfl_down(1)
__device__ __forceinline__ float wshr1(float x) { return updpp0<0x138, 0xF>(x); }
__device__ __forceinline__ float wshl1(float x) { return updpp0<0x130, 0xF>(x); }

// atomic-fallback init (only if ws is too small for slots)
__global__ void init_ws_kernel(unsigned int* ws) {
    ws[0] = 0x7F800000u;  // +inf
    ws[1] = 0xFF800000u;  // -inf
}

// ---------------------------------------------------------------------------
// One wave handles RPW=8 consecutive rays. Per ray: samples j=0..95,
// batch a = lane l (j=l), batch b = lane l (j=64+l, l<32).
// Log-space: dd2_i = (d_{i+1}-d_i)*log2(1+exp(x_i)); T_j = exp2(-prefix).
// w_i = T_i - T_{i+1}; v_j = 0.5*(T_{j-1}-T_{j+1}); 1-wtot = T_95.
// Per-block depth bounds -> slot array in ws (or atomics fallback).
// Depth stored raw (NaN->inf); tail_kernel clamps.
// ---------------------------------------------------------------------------
template <bool SLOT>
__global__ __launch_bounds__(256) void march_kernel(
    const float* __restrict__ colors,
    const float* __restrict__ dens,
    const float* __restrict__ depths,
    const int* __restrict__ white_back,
    unsigned int* __restrict__ ws,
    float* __restrict__ out_rgb,   // [nrays,3]
    float* __restrict__ out_dep,   // [nrays] raw
    float* __restrict__ out_w,     // [nrays,95]
    int nrays, int nblocks) {
    const int wv = threadIdx.x >> 6;
    const int l = threadIdx.x & 63;
    const int waveId = blockIdx.x * 4 + wv;
    const int wb = *white_back;
    const float C1 = 0.5f * L2E;

    float mn = INFINITY, mx = -INFINITY;

#pragma unroll 2
    for (int it = 0; it < RPW; ++it) {
        const int ray = waveId * RPW + it;       // wave-uniform
        if (ray >= nrays) break;

        const float* db = depths + (size_t)ray * S;
        const float* sb = dens + (size_t)ray * S;
        const float* cb = colors + (size_t)ray * (3 * S);

        float d_a = db[l];
        float s_a = sb[l];
        float c0_a = cb[3 * l + 0];
        float c1_a = cb[3 * l + 1];
        float c2_a = cb[3 * l + 2];
        const bool hb = (l < 32);
        float d_b = hb ? db[64 + l] : 0.f;
        float s_b = hb ? sb[64 + l] : 0.f;
        float c0_b = hb ? cb[192 + 3 * l + 0] : 0.f;
        float c1_b = hb ? cb[192 + 3 * l + 1] : 0.f;
        float c2_b = hb ? cb[192 + 3 * l + 2] : 0.f;

        // ray depth bounds (sorted): d[0]=lane0 d_a, d[95]=lane31 d_b
        mn = fminf(mn, rdlane(d_a, 0));
        mx = fmaxf(mx, rdlane(d_b, 31));

        // neighbors via wave shifts (VALU)
        float dn_a = wshl1(d_a);
        float sn_a = wshl1(s_a);
        {
            float d64 = rdlane(d_b, 0);
            float s64 = rdlane(s_b, 0);
            if (l == 63) { dn_a = d64; sn_a = s64; }
        }
        float dn_b = wshl1(d_b);
        float sn_b = wshl1(s_b);

        // log2-space density*delta per midpoint
        float x_a = (s_a + sn_a) * C1;
        float lg_a = fmaxf(x_a, 0.f) + flog2(1.f + fexp2(-fabsf(x_a)));
        float dd_a = (dn_a - d_a) * lg_a;                    // midpoint l
        float x_b = (s_b + sn_b) * C1;
        float lg_b = fmaxf(x_b, 0.f) + flog2(1.f + fexp2(-fabsf(x_b)));
        float dd_b = (l <= 30) ? (dn_b - d_b) * lg_b : 0.f;  // midpoint 64+l

        // DPP scans
        float A = dpp_scan_add(dd_a);
        float P = rdlane(A, 63);
        float Bc = dpp_scan_add(dd_b);

        float Ti_a = fexp2(-A);              // T_{l+1}
        float Ti_b = fexp2(-(P + Bc));       // T_{65+l} (l=31 -> T_96:=T_95)
        float T63 = rdlane(Ti_a, 62);
        float T64 = rdlane(Ti_a, 63);
        float T95 = rdlane(Ti_b, 31);

        float Te_a = wshr1(Ti_a);            // T_l
        if (l == 0) Te_a = 1.f;
        float Te_b = wshr1(Ti_b);            // T_{64+l}
        if (l == 0) Te_b = T64;
        float Tm1_a = wshr1(Te_a);           // T_{l-1} (lane1 <- Te_a[0]=1 ok)
        if (l == 0) Tm1_a = 1.f;             // T_{-1} := 1
        float Tm1_b = wshr1(Te_b);           // T_{63+l} (lane1 <- T64 ok)
        if (l == 0) Tm1_b = T63;

        float w_a = Te_a - Ti_a;             // weight midpoint l
        float w_b = Te_b - Ti_b;             // weight midpoint 64+l (l<=30)
        float v_a = 0.5f * (Tm1_a - Ti_a);           // coeff sample l
        float v_b = hb ? 0.5f * (Tm1_b - Ti_b) : 0.f;  // coeff sample 64+l

        float r_sum = wave_sum(v_a * c0_a + v_b * c0_b);
        float g_sum = wave_sum(v_a * c1_a + v_b * c1_b);
        float b_sum = wave_sum(v_a * c2_a + v_b * c2_b);
        float dep_sum = wave_sum(v_a * d_a + v_b * d_b);

        float* wout = out_w + (size_t)ray * SM;
        wout[l] = w_a;                    // midpoints 0..63
        if (l <= 30) wout[64 + l] = w_b;  // midpoints 64..94

        if (l == 0) {
            float rr = r_sum, gg = g_sum, bb = b_sum;
            if (wb) { rr += T95; gg += T95; bb += T95; }  // 1-wtot = T_95
            out_rgb[(size_t)ray * 3 + 0] = rr;
            out_rgb[(size_t)ray * 3 + 1] = gg;
            out_rgb[(size_t)ray * 3 + 2] = bb;
            float cd = dep_sum;
            if (isnan(cd)) cd = INFINITY;   // nan_to_num(nan=inf)
            out_dep[ray] = cd;              // clamped by tail_kernel
        }
    }

    // block min/max -> slot (or atomics)
    __shared__ float smn[4], smx[4];
    if (l == 0) { smn[wv] = mn; smx[wv] = mx; }
    __syncthreads();
    if (threadIdx.x == 0) {
        float bmn = fminf(fminf(smn[0], smn[1]), fminf(smn[2], smn[3]));
        float bmx = fmaxf(fmaxf(smx[0], smx[1]), fmaxf(smx[2], smx[3]));
        if (SLOT) {
            float* sl = (float*)ws;
            sl[2 + blockIdx.x] = bmn;
            sl[2 + nblocks + blockIdx.x] = bmx;
        } else {
            atomicMin((int*)&ws[0], __float_as_int(bmn));
            atomicMax((int*)&ws[1], __float_as_int(bmx));
        }
    }
}

// Merged finalize+clamp: every block redundantly reduces the slot array
// (L2-resident, tiny) then clamps its contiguous chunk of out_dep.
__global__ __launch_bounds__(256) void tail_kernel(
    float* __restrict__ dep, const unsigned int* __restrict__ ws,
    int n, int nblocks, int slotMode) {
    float gmn, gmx;
    if (slotMode) {
        const float* sl = (const float*)ws + 2;
        float mn = INFINITY, mx = -INFINITY;
        for (int i = threadIdx.x; i < nblocks; i += 256) {
            mn = fminf(mn, sl[i]);
            mx = fmaxf(mx, sl[i + nblocks]);
        }
#pragma unroll
        for (int off = 32; off >= 1; off >>= 1) {
            mn = fminf(mn, __shfl_xor(mn, off));
            mx = fmaxf(mx, __shfl_xor(mx, off));
        }
        __shared__ float a[4], b[4];
        const int wv = threadIdx.x >> 6;
        if ((threadIdx.x & 63) == 0) { a[wv] = mn; b[wv] = mx; }
        __syncthreads();
        gmn = fminf(fminf(a[0], a[1]), fminf(a[2], a[3]));
        gmx = fmaxf(fmaxf(b[0], b[1]), fmaxf(b[2], b[3]));
    } else {
        gmn = __int_as_float((int)ws[0]);
        gmx = __int_as_float((int)ws[1]);
    }
    int i = blockIdx.x * 256 + threadIdx.x;
    if (i < n) dep[i] = fminf(fmaxf(dep[i], gmn), gmx);
}

extern "C" void kernel_launch(void* const* d_in, const int* in_sizes, int n_in,
                              void* d_out, int out_size, void* d_ws, size_t ws_size,
                              hipStream_t stream) {
    const float* colors = (const float*)d_in[0];
    const float* dens = (const float*)d_in[1];
    const float* depths = (const float*)d_in[2];
    const int* white_back = (const int*)d_in[3];

    const int nrays = in_sizes[1] / S;  // densities: nrays * S
    unsigned int* ws = (unsigned int*)d_ws;

    float* out_rgb = (float*)d_out;                // nrays*3
    float* out_dep = out_rgb + (size_t)nrays * 3;  // nrays
    float* out_w = out_dep + nrays;                // nrays*95

    const int raysPerBlock = RPW * 4;              // 4 waves/block
    const int nblocks = (nrays + raysPerBlock - 1) / raysPerBlock;
    const bool slot = ws_size >= (size_t)(2 + 2 * nblocks) * sizeof(float);

    if (slot) {
        march_kernel<true><<<nblocks, 256, 0, stream>>>(
            colors, dens, depths, white_back, ws, out_rgb, out_dep, out_w,
            nrays, nblocks);
    } else {
        init_ws_kernel<<<1, 1, 0, stream>>>(ws);
        march_kernel<false><<<nblocks, 256, 0, stream>>>(
            colors, dens, depths, white_back, ws, out_rgb, out_dep, out_w,
            nrays, nblocks);
    }
    tail_kernel<<<(nrays + 255) / 256, 256, 0, stream>>>(
        out_dep, ws, nrays, nblocks, slot ? 1 : 0);
}